// Round 1
// baseline (571.583 us; speedup 1.0000x reference)
//
#include <hip/hip_runtime.h>

// FeatureGrid: trilinear interp of N points into (C=32, 128^3) f32 grid.
// Strategy: transpose feature (C,S) -> (S,C) in workspace so each corner
// gather is a contiguous 128-B segment, then 8 threads/point gather kernel.

constexpr int   GD      = 128;                         // grid dim per axis
constexpr long long SPATIAL = (long long)GD * GD * GD; // 2097152
constexpr int   FD      = 32;                          // channels
constexpr float PLO     = -10.0f;
constexpr float PHI     = 10.0f;

// ---------------- transpose (C, S) -> (S, C) ----------------
// tile: 32 channels x 64 spatial per block; 256 threads.
// global reads: wave = 64 lanes read 64 consecutive s for one c (256 B contig)
// global writes: wave writes 2 points x 32 ch contiguous (256 B contig)
// LDS stride 33 -> max 2-way bank aliasing (free on gfx950).
__global__ __launch_bounds__(256) void transpose_feat(
    const float* __restrict__ f, float* __restrict__ o) {
    __shared__ float lds[64][FD + 1];
    const int t  = threadIdx.x;
    const int s0 = blockIdx.x * 64;
    const int sl = t & 63;   // spatial within tile
    const int cq = t >> 6;   // 0..3
#pragma unroll
    for (int it = 0; it < 8; ++it) {
        const int c = it * 4 + cq;
        lds[sl][c] = f[(size_t)c * SPATIAL + s0 + sl];
    }
    __syncthreads();
    const int cw  = t & 31;  // channel
    const int swb = t >> 5;  // 0..7
#pragma unroll
    for (int it = 0; it < 8; ++it) {
        const int s = swb + it * 8;
        o[(size_t)(s0 + s) * FD + cw] = lds[s][cw];
    }
}

// ---------------- gather: 8 threads per point ----------------
__global__ __launch_bounds__(256) void trilerp(
    const float* __restrict__ x, const float* __restrict__ ft,
    float* __restrict__ out, int npts) {
    const int tid = blockIdx.x * 256 + threadIdx.x;
    const int n = tid >> 3;
    if (n >= npts) return;
    const int j = tid & 7;  // channel quad

    const float px = x[3 * n + 0];
    const float py = x[3 * n + 1];
    const float pz = x[3 * n + 2];

    // match reference arithmetic order
    const float cx = 2.0f * (px - PLO) / (PHI - PLO) - 1.0f;
    const float cy = 2.0f * (py - PLO) / (PHI - PLO) - 1.0f;
    const float cz = 2.0f * (pz - PLO) / (PHI - PLO) - 1.0f;
    const float fx = ((cx + 1.0f) * GD - 1.0f) * 0.5f;
    const float fy = ((cy + 1.0f) * GD - 1.0f) * 0.5f;
    const float fz = ((cz + 1.0f) * GD - 1.0f) * 0.5f;

    const float x0f = floorf(fx), y0f = floorf(fy), z0f = floorf(fz);
    const float wx = fx - x0f, wy = fy - y0f, wz = fz - z0f;
    const int x0 = (int)x0f, y0 = (int)y0f, z0 = (int)z0f;

    float4 acc = make_float4(0.f, 0.f, 0.f, 0.f);
#pragma unroll
    for (int dz = 0; dz < 2; ++dz) {
#pragma unroll
        for (int dy = 0; dy < 2; ++dy) {
#pragma unroll
            for (int dx = 0; dx < 2; ++dx) {
                const int xi = x0 + dx, yi = y0 + dy, zi = z0 + dz;
                const bool valid = ((unsigned)xi < (unsigned)GD) &
                                   ((unsigned)yi < (unsigned)GD) &
                                   ((unsigned)zi < (unsigned)GD);
                float w = (dx ? wx : 1.0f - wx) * (dy ? wy : 1.0f - wy) *
                          (dz ? wz : 1.0f - wz);
                w = valid ? w : 0.0f;
                const int xc = min(max(xi, 0), GD - 1);
                const int yc = min(max(yi, 0), GD - 1);
                const int zc = min(max(zi, 0), GD - 1);
                const size_t idx = (size_t)(zc * GD + yc) * GD + xc;
                const float4 v =
                    *reinterpret_cast<const float4*>(ft + idx * FD + j * 4);
                acc.x = fmaf(v.x, w, acc.x);
                acc.y = fmaf(v.y, w, acc.y);
                acc.z = fmaf(v.z, w, acc.z);
                acc.w = fmaf(v.w, w, acc.w);
            }
        }
    }
    *reinterpret_cast<float4*>(out + (size_t)n * FD + j * 4) = acc;
}

// ---------------- fallback: direct gather in (C,S) layout ----------------
__global__ __launch_bounds__(256) void trilerp_direct(
    const float* __restrict__ x, const float* __restrict__ f,
    float* __restrict__ out, int npts) {
    const int tid = blockIdx.x * 256 + threadIdx.x;
    const int n = tid >> 3;
    if (n >= npts) return;
    const int j = tid & 7;

    const float px = x[3 * n + 0];
    const float py = x[3 * n + 1];
    const float pz = x[3 * n + 2];
    const float cx = 2.0f * (px - PLO) / (PHI - PLO) - 1.0f;
    const float cy = 2.0f * (py - PLO) / (PHI - PLO) - 1.0f;
    const float cz = 2.0f * (pz - PLO) / (PHI - PLO) - 1.0f;
    const float fx = ((cx + 1.0f) * GD - 1.0f) * 0.5f;
    const float fy = ((cy + 1.0f) * GD - 1.0f) * 0.5f;
    const float fz = ((cz + 1.0f) * GD - 1.0f) * 0.5f;
    const float x0f = floorf(fx), y0f = floorf(fy), z0f = floorf(fz);
    const float wx = fx - x0f, wy = fy - y0f, wz = fz - z0f;
    const int x0 = (int)x0f, y0 = (int)y0f, z0 = (int)z0f;

    float acc[4] = {0.f, 0.f, 0.f, 0.f};
#pragma unroll
    for (int dz = 0; dz < 2; ++dz)
#pragma unroll
        for (int dy = 0; dy < 2; ++dy)
#pragma unroll
            for (int dx = 0; dx < 2; ++dx) {
                const int xi = x0 + dx, yi = y0 + dy, zi = z0 + dz;
                const bool valid = ((unsigned)xi < (unsigned)GD) &
                                   ((unsigned)yi < (unsigned)GD) &
                                   ((unsigned)zi < (unsigned)GD);
                float w = (dx ? wx : 1.0f - wx) * (dy ? wy : 1.0f - wy) *
                          (dz ? wz : 1.0f - wz);
                w = valid ? w : 0.0f;
                const int xc = min(max(xi, 0), GD - 1);
                const int yc = min(max(yi, 0), GD - 1);
                const int zc = min(max(zi, 0), GD - 1);
                const size_t idx = (size_t)(zc * GD + yc) * GD + xc;
#pragma unroll
                for (int k = 0; k < 4; ++k)
                    acc[k] = fmaf(f[(size_t)(j * 4 + k) * SPATIAL + idx], w, acc[k]);
            }
#pragma unroll
    for (int k = 0; k < 4; ++k) out[(size_t)n * FD + j * 4 + k] = acc[k];
}

extern "C" void kernel_launch(void* const* d_in, const int* in_sizes, int n_in,
                              void* d_out, int out_size, void* d_ws, size_t ws_size,
                              hipStream_t stream) {
    const float* x    = (const float*)d_in[0];
    const float* feat = (const float*)d_in[1];
    float*       out  = (float*)d_out;
    const int npts = in_sizes[0] / 3;

    const size_t need = (size_t)SPATIAL * FD * sizeof(float);  // 256 MiB
    const int gblocks = (npts * 8 + 255) / 256;

    if (ws_size >= need) {
        float* ft = (float*)d_ws;
        transpose_feat<<<(int)(SPATIAL / 64), 256, 0, stream>>>(feat, ft);
        trilerp<<<gblocks, 256, 0, stream>>>(x, ft, out, npts);
    } else {
        trilerp_direct<<<gblocks, 256, 0, stream>>>(x, feat, out, npts);
    }
}